// Round 3
// baseline (438.050 us; speedup 1.0000x reference)
//
#include <hip/hip_runtime.h>
#include <math.h>

#define NN 8192
#define DD 128
#define THRESH 0.15f

typedef __attribute__((ext_vector_type(8))) short short8;
typedef __attribute__((ext_vector_type(4))) float f32x4;

// round-to-nearest-even f32 -> bf16 bits
__device__ __forceinline__ unsigned short f2bf(float f) {
    unsigned int u = __float_as_uint(f);
    return (unsigned short)((u + 0x7fffu + ((u >> 16) & 1u)) >> 16);
}

// insert (v,j) into sorted-desc top-8 (tie: smaller index first)
__device__ __forceinline__ void ins8(float v, int j, float* tv, int* ti) {
    bool in = (v > tv[7]) | ((v == tv[7]) & (j < ti[7]));
    if (!in) return;
#pragma unroll
    for (int s = 7; s >= 1; --s) {
        bool up = (v > tv[s - 1]) | ((v == tv[s - 1]) & (j < ti[s - 1]));
        tv[s] = up ? tv[s - 1] : v;
        ti[s] = up ? ti[s - 1] : j;
        if (!up) return;
    }
    tv[0] = v; ti[0] = j;
}

// ------- K1: normalize rows, emit bf16 x-hat (row-major, k-contiguous) -------
__global__ __launch_bounds__(256) void norm_rows(const float* __restrict__ x,
                                                 unsigned int* __restrict__ xb) {
    const int t = threadIdx.x;
    const int lane = t & 63;
    const int i = blockIdx.x * 4 + (t >> 6);
    float2 v = reinterpret_cast<const float2*>(x + (size_t)i * DD)[lane];
    float ss = v.x * v.x + v.y * v.y;
#pragma unroll
    for (int d = 1; d < 64; d <<= 1) ss += __shfl_xor(ss, d);
    float inv = 1.0f / fmaxf(sqrtf(ss), 1e-12f);
    xb[(size_t)i * 64 + lane] = ((unsigned int)f2bf(v.y * inv) << 16) | f2bf(v.x * inv);
}

// ------- K2: role-split — half the blocks zero-fill d_out (plain cached
// stores, fillBuffer-style), half run the MFMA sim sweep + per-row top-8.
// Roles alternate per group of 8 consecutive blockIdx so both roles land on
// every XCD regardless of the (round-robin) workgroup->XCD mapping. -------
__global__ __launch_bounds__(256, 4) void build_fused(const unsigned int* __restrict__ xbw,
                                                      int* __restrict__ cidx,
                                                      float* __restrict__ out) {
    const int t   = threadIdx.x;
    const int grp = blockIdx.x >> 3;
    const int sub = (grp >> 1) * 8 + (blockIdx.x & 7);   // 0..511 within role

    if (grp & 1) {
        // ---- fill role: zero a contiguous 1 MB chunk of d_out (both arrays) ----
        f32x4* dst = reinterpret_cast<f32x4*>(out) + (size_t)sub * 65536 + t;
        const f32x4 z = {0.f, 0.f, 0.f, 0.f};
#pragma unroll 4
        for (int m = 0; m < 256; ++m)
            dst[(size_t)m * 256] = z;
        return;
    }

    // ---- compute role: 16 rows, full 8192-candidate sweep ----
    __shared__ float smv[16][4][8];
    __shared__ int   smi[16][4][8];
    const int lane = t & 63;
    const int w    = t >> 6;          // wave 0..3 -> candidate strip
    const int i0   = sub * 16;
    const int l15  = lane & 15;
    const int lh   = lane >> 4;       // 0..3
    const int i    = i0 + l15;        // this lane's output row
    const short* xbs = reinterpret_cast<const short*>(xbw);

    // B-operand frags: lane holds xhat[i0+l15][kc*32 + lh*8 .. +7]
    short8 rf[4];
#pragma unroll
    for (int kc = 0; kc < 4; ++kc)
        rf[kc] = *reinterpret_cast<const short8*>(xbs + (size_t)i * DD + kc * 32 + lh * 8);

    float tv[8]; int ti[8];
#pragma unroll
    for (int s = 0; s < 8; ++s) { tv[s] = -1e30f; ti[s] = 0x7fffffff; }

    const int jbase = w * 2048;
    const short* cbase = xbs + (size_t)(jbase + l15) * DD + lh * 8;  // += jc*16*DD per chunk

    // software pipeline: ping-pong A-operand fragments (16 candidates/chunk)
    short8 a0, a1, a2, a3, b0, b1, b2, b3;
    a0 = *reinterpret_cast<const short8*>(cbase + 0);
    a1 = *reinterpret_cast<const short8*>(cbase + 32);
    a2 = *reinterpret_cast<const short8*>(cbase + 64);
    a3 = *reinterpret_cast<const short8*>(cbase + 96);

    for (int jc = 0; jc < 128; jc += 2) {
        {   // prefetch chunk jc+1
            const short* pb = cbase + (size_t)((jc + 1) & 127) * 16 * DD;
            b0 = *reinterpret_cast<const short8*>(pb + 0);
            b1 = *reinterpret_cast<const short8*>(pb + 32);
            b2 = *reinterpret_cast<const short8*>(pb + 64);
            b3 = *reinterpret_cast<const short8*>(pb + 96);
        }
        {   // compute chunk jc
            f32x4 acc = {0.f, 0.f, 0.f, 0.f};
            acc = __builtin_amdgcn_mfma_f32_16x16x32_bf16(a0, rf[0], acc, 0, 0, 0);
            acc = __builtin_amdgcn_mfma_f32_16x16x32_bf16(a1, rf[1], acc, 0, 0, 0);
            acc = __builtin_amdgcn_mfma_f32_16x16x32_bf16(a2, rf[2], acc, 0, 0, 0);
            acc = __builtin_amdgcn_mfma_f32_16x16x32_bf16(a3, rf[3], acc, 0, 0, 0);
            const int j0 = jbase + jc * 16 + lh * 4;
#pragma unroll
            for (int r = 0; r < 4; ++r) {
                int j = j0 + r;
                if (j != i) ins8(acc[r], j, tv, ti);
            }
        }
        {   // prefetch chunk jc+2 (wraps harmlessly at the end)
            const short* pa = cbase + (size_t)((jc + 2) & 127) * 16 * DD;
            a0 = *reinterpret_cast<const short8*>(pa + 0);
            a1 = *reinterpret_cast<const short8*>(pa + 32);
            a2 = *reinterpret_cast<const short8*>(pa + 64);
            a3 = *reinterpret_cast<const short8*>(pa + 96);
        }
        {   // compute chunk jc+1
            f32x4 acc = {0.f, 0.f, 0.f, 0.f};
            acc = __builtin_amdgcn_mfma_f32_16x16x32_bf16(b0, rf[0], acc, 0, 0, 0);
            acc = __builtin_amdgcn_mfma_f32_16x16x32_bf16(b1, rf[1], acc, 0, 0, 0);
            acc = __builtin_amdgcn_mfma_f32_16x16x32_bf16(b2, rf[2], acc, 0, 0, 0);
            acc = __builtin_amdgcn_mfma_f32_16x16x32_bf16(b3, rf[3], acc, 0, 0, 0);
            const int j0 = jbase + (jc + 1) * 16 + lh * 4;
#pragma unroll
            for (int r = 0; r < 4; ++r) {
                int j = j0 + r;
                if (j != i) ins8(acc[r], j, tv, ti);
            }
        }
    }

    // merge the 4 lane-groups sharing row i (lanes l, l+16, l+32, l+48)
#pragma unroll
    for (int d = 16; d < 64; d <<= 1) {
        float ov[8]; int oi[8];
#pragma unroll
        for (int s = 0; s < 8; ++s) { ov[s] = __shfl_xor(tv[s], d); oi[s] = __shfl_xor(ti[s], d); }
#pragma unroll
        for (int s = 0; s < 8; ++s) ins8(ov[s], oi[s], tv, ti);
    }
    if (lane < 16) {
#pragma unroll
        for (int s = 0; s < 8; ++s) { smv[lane][w][s] = tv[s]; smi[lane][w][s] = ti[s]; }
    }
    __syncthreads();
    if (t < 16) {
        float mv[8]; int mi[8];
#pragma unroll
        for (int s = 0; s < 8; ++s) { mv[s] = smv[t][0][s]; mi[s] = smi[t][0][s]; }
#pragma unroll
        for (int ww = 1; ww < 4; ++ww)
#pragma unroll
            for (int s = 0; s < 8; ++s) ins8(smv[t][ww][s], smi[t][ww][s], mv, mi);
#pragma unroll
        for (int s = 0; s < 8; ++s) cidx[(size_t)(i0 + t) * 8 + s] = mi[s];
    }
}

// ------- K3: exact fp32 re-rank of 8 candidates, scatter adj/ew -------
__global__ __launch_bounds__(256) void rerank(const float* __restrict__ x,
                                              const int* __restrict__ cidx,
                                              float* __restrict__ adj,
                                              float* __restrict__ ew) {
    const int t = threadIdx.x;
    const int lane = t & 63;
    const int i = blockIdx.x * 4 + (t >> 6);
    float2 a = reinterpret_cast<const float2*>(x + (size_t)i * DD)[lane];
    float ss = a.x * a.x + a.y * a.y;
#pragma unroll
    for (int d = 1; d < 64; d <<= 1) ss += __shfl_xor(ss, d);
    float ni = fmaxf(sqrtf(ss), 1e-12f);

    int myc = (lane < 8) ? cidx[(size_t)i * 8 + lane] : 0;
    float sv[8]; int jv[8];
#pragma unroll
    for (int c = 0; c < 8; ++c) {
        int j = __shfl(myc, c);
        float2 b = reinterpret_cast<const float2*>(x + (size_t)j * DD)[lane];
        float dp = a.x * b.x + a.y * b.y;
        float sb = b.x * b.x + b.y * b.y;
#pragma unroll
        for (int d = 1; d < 64; d <<= 1) { dp += __shfl_xor(dp, d); sb += __shfl_xor(sb, d); }
        float nj = fmaxf(sqrtf(sb), 1e-12f);
        sv[c] = dp / (ni * nj);
        jv[c] = j;
    }
    if (lane == 0) {
#pragma unroll
        for (int c = 0; c < 8; ++c) {
            int beats = 0;
#pragma unroll
            for (int c2 = 0; c2 < 8; ++c2)
                beats += ((sv[c2] > sv[c]) | ((sv[c2] == sv[c]) & (jv[c2] < jv[c]))) ? 1 : 0;
            if (beats < 4 && sv[c] > THRESH) {
                adj[(size_t)i * NN + jv[c]] = 1.0f;
                ew [(size_t)i * NN + jv[c]] = sv[c];
            }
        }
    }
}

extern "C" void kernel_launch(void* const* d_in, const int* in_sizes, int n_in,
                              void* d_out, int out_size, void* d_ws, size_t ws_size,
                              hipStream_t stream) {
    const float* x = (const float*)d_in[0];
    unsigned int* xb = (unsigned int*)d_ws;                 // 2 MB bf16 x-hat
    int* cidx = (int*)((char*)d_ws + (2u << 20));           // 256 KB candidate indices
    float* adj = (float*)d_out;
    float* ew  = adj + (size_t)NN * NN;
    hipLaunchKernelGGL(norm_rows,   dim3(NN / 4),  dim3(256), 0, stream, x, xb);
    hipLaunchKernelGGL(build_fused, dim3(1024),    dim3(256), 0, stream, xb, cidx, adj);
    hipLaunchKernelGGL(rerank,      dim3(NN / 4),  dim3(256), 0, stream, x, cidx, adj, ew);
}